// Round 6
// baseline (767.290 us; speedup 1.0000x reference)
//
#include <hip/hip_runtime.h>

#define IN_CH 128
#define OUT_CH 64
#define BN 64         // nodes per bucket
#define CAP 1280      // sparse slots per bucket (mean 1024, sigma 32 -> 8 sigma)
#define NPART 256     // partition blocks

typedef __attribute__((ext_vector_type(8))) short short8;
typedef __attribute__((ext_vector_type(4))) float f32x4;

__device__ __forceinline__ unsigned short f2bf(float f) {
    unsigned u = __float_as_uint(f);
    unsigned r = (u + 0x7FFFu + ((u >> 16) & 1u)) >> 16;   // RNE
    return (unsigned short)r;
}

// ---------- part1: fused hist + range-reservation + scatter (sparse) ----------
__global__ __launch_bounds__(1024) void k_part1(const int* __restrict__ row,
                                                const int* __restrict__ col,
                                                const float* __restrict__ ew,
                                                int* __restrict__ cnt,
                                                uint2* __restrict__ sparse,
                                                int E, int per, int nbuck) {
    __shared__ int lh[1600];
    __shared__ int cur[1600];
    int tid = threadIdx.x;
    for (int i = tid; i < nbuck; i += 1024) lh[i] = 0;
    __syncthreads();
    int e0 = blockIdx.x * per;
    int e1 = min(E, e0 + per);
    for (int e = e0 + tid; e < e1; e += 1024)
        atomicAdd(&lh[col[e] >> 6], 1);
    __syncthreads();
    for (int bin = tid; bin < nbuck; bin += 1024) {
        int c = lh[bin];
        int base = c ? atomicAdd(&cnt[bin], c) : 0;   // reserve range in bucket
        cur[bin] = bin * CAP + base;
    }
    __syncthreads();
    int lim = nbuck * CAP;
    for (int e = e0 + tid; e < e1; e += 1024) {
        int r = row[e];
        int c = col[e];
        float w = ew[e];
        int bin = c >> 6;
        int p = atomicAdd(&cur[bin], 1);
        if (p < lim)   // safety clamp (never triggers at 8 sigma)
            sparse[p] = make_uint2((unsigned)r | ((unsigned)(c & 63) << 17),
                                   __float_as_uint(w));
    }
}

// ---------- gemm3: fused per-bucket degree + dis + MFMA bf16 GEMM ----------
__global__ __launch_bounds__(256) void k_gemm3(const float* __restrict__ x,
                                               const float* __restrict__ W,
                                               const uint2* __restrict__ sparse,
                                               const int* __restrict__ cnt,
                                               float* __restrict__ dis,
                                               unsigned short* __restrict__ hb,
                                               int N) {
    __shared__ unsigned short Wl[64][136];   // W^T bf16, padded: row stride 272B (17x16B)
    __shared__ float degs[BN];

    int tid = threadIdx.x;
    int b = blockIdx.x;
    int row0 = b * BN;

    if (tid < BN) degs[tid] = 0.f;
    __syncthreads();

    // stage W transposed to bf16 LDS (one-time, L1/L2-hot) ...
    for (int i = tid; i < 2048; i += 256) {
        int k = i >> 4;             // 0..127
        int n4 = (i & 15) << 2;     // 0,4,...,60
        float4 v = *(const float4*)(W + (size_t)k * OUT_CH + n4);
        Wl[n4 + 0][k] = f2bf(v.x);
        Wl[n4 + 1][k] = f2bf(v.y);
        Wl[n4 + 2][k] = f2bf(v.z);
        Wl[n4 + 3][k] = f2bf(v.w);
    }
    // ... overlapped with per-bucket weighted degree from sparse
    {
        int m = min(cnt[b], CAP);
        int sbase = b * CAP;
        for (int i = tid; i < m; i += 256) {
            uint2 r = sparse[sbase + i];
            atomicAdd(&degs[(r.x >> 17) & 63], __uint_as_float(r.y));
        }
    }
    __syncthreads();

    if (tid < BN) {
        float d = degs[tid];
        float dv = (d > 0.f) ? rsqrtf(d) : 0.f;
        int node = row0 + tid;
        if (node < N) dis[node] = dv;
        degs[tid] = dv;              // reuse as dis for epilogue (sync'd below)
    }

    // MFMA: wave w owns rows [16w, 16w+16); 4 n-tiles of 16 cover OUT=64
    int lane = tid & 63;
    int wv = tid >> 6;
    int r0l = 16 * wv;
    int cn = lane & 15;
    int rg = lane >> 4;              // k-group / row-group

    f32x4 acc0 = {0.f, 0.f, 0.f, 0.f};
    f32x4 acc1 = {0.f, 0.f, 0.f, 0.f};
    f32x4 acc2 = {0.f, 0.f, 0.f, 0.f};
    f32x4 acc3 = {0.f, 0.f, 0.f, 0.f};

    int arow = row0 + r0l + cn;      // A-fragment row for this lane
#pragma unroll
    for (int ks = 0; ks < 4; ++ks) {
        int k0 = ks * 32 + rg * 8;
        short8 a = {};
        if (arow < N) {
            const float* xp = x + (size_t)arow * IN_CH + k0;
            float4 va = *(const float4*)(xp);
            float4 vb = *(const float4*)(xp + 4);
            a[0] = (short)f2bf(va.x); a[1] = (short)f2bf(va.y);
            a[2] = (short)f2bf(va.z); a[3] = (short)f2bf(va.w);
            a[4] = (short)f2bf(vb.x); a[5] = (short)f2bf(vb.y);
            a[6] = (short)f2bf(vb.z); a[7] = (short)f2bf(vb.w);
        }
        short8 b0 = *(const short8*)&Wl[ 0 + cn][k0];
        short8 b1 = *(const short8*)&Wl[16 + cn][k0];
        short8 b2 = *(const short8*)&Wl[32 + cn][k0];
        short8 b3 = *(const short8*)&Wl[48 + cn][k0];
        acc0 = __builtin_amdgcn_mfma_f32_16x16x32_bf16(a, b0, acc0, 0, 0, 0);
        acc1 = __builtin_amdgcn_mfma_f32_16x16x32_bf16(a, b1, acc1, 0, 0, 0);
        acc2 = __builtin_amdgcn_mfma_f32_16x16x32_bf16(a, b2, acc2, 0, 0, 0);
        acc3 = __builtin_amdgcn_mfma_f32_16x16x32_bf16(a, b3, acc3, 0, 0, 0);
    }
    __syncthreads();   // dis values in degs[] now visible

    // C/D layout (m89-verified): col = lane&15, row = (lane>>4)*4 + reg
#pragma unroll
    for (int r = 0; r < 4; ++r) {
        int row_l = r0l + rg * 4 + r;
        int grow = row0 + row_l;
        if (grow < N) {
            float sc = degs[row_l];
            unsigned short* hp = hb + (size_t)grow * OUT_CH + cn;
            hp[ 0] = f2bf(acc0[r] * sc);
            hp[16] = f2bf(acc1[r] * sc);
            hp[32] = f2bf(acc2[r] * sc);
            hp[48] = f2bf(acc3[r] * sc);
        }
    }
}

// ---------- agg: flat edge-parallel gather + LDS f32 atomic accumulation ----------
// Replaces sort3's hist/scan/regroup. Records are padded to a multiple of 32 with
// zero-weight entries -> zero divergence, all gather loads independent (max MLP).
// ds_add_f32 is no-return fire-and-forget: the only waits are the gathers.
__global__ __launch_bounds__(256) void k_agg(const uint2* __restrict__ sparse,
                                             const int* __restrict__ cnt,
                                             const float* __restrict__ dis,
                                             const unsigned short* __restrict__ hb,
                                             const float* __restrict__ bias,
                                             float* __restrict__ out,
                                             int N, int nbuck) {
    __shared__ uint2 recbuf[CAP];          // 10 KB
    __shared__ float acc[BN][OUT_CH];      // 16 KB; ds_add bank pattern = 2-way (free)

    int b = blockIdx.x;
    int tid = threadIdx.x;
    int sbase = b * CAP;
    int m = min(cnt[b], CAP);
    int mp = (m + 31) & ~31;               // pad to multiple of 32 (<= CAP)

    float* az = &acc[0][0];
    for (int i = tid; i < BN * OUT_CH; i += 256) az[i] = 0.f;
    for (int i = tid; i < mp; i += 256)
        recbuf[i] = (i < m) ? sparse[sbase + i] : make_uint2(0u, 0u);  // w=0 pad
    __syncthreads();

    int hw = tid >> 5;                     // half-wave 0..7
    int lanep = tid & 31;
    unsigned co = 2u * (unsigned)lanep;    // channel pair offset (shorts)

    for (int i = hw * 4; i < mp; i += 32) {
        uint2 r0 = recbuf[i + 0];          // LDS broadcast (all 32 lanes same addr)
        uint2 r1 = recbuf[i + 1];
        uint2 r2 = recbuf[i + 2];
        uint2 r3 = recbuf[i + 3];
        unsigned v0 = *(const unsigned*)(hb + (((size_t)(r0.x & 0x1FFFFu)) << 6) + co);
        unsigned v1 = *(const unsigned*)(hb + (((size_t)(r1.x & 0x1FFFFu)) << 6) + co);
        unsigned v2 = *(const unsigned*)(hb + (((size_t)(r2.x & 0x1FFFFu)) << 6) + co);
        unsigned v3 = *(const unsigned*)(hb + (((size_t)(r3.x & 0x1FFFFu)) << 6) + co);
        float w0 = __uint_as_float(r0.y);
        float w1 = __uint_as_float(r1.y);
        float w2 = __uint_as_float(r2.y);
        float w3 = __uint_as_float(r3.y);
        int d0 = (r0.x >> 17) & 63;
        int d1 = (r1.x >> 17) & 63;
        int d2 = (r2.x >> 17) & 63;
        int d3 = (r3.x >> 17) & 63;
        atomicAdd(&acc[d0][co],     w0 * __uint_as_float(v0 << 16));
        atomicAdd(&acc[d0][co + 1], w0 * __uint_as_float(v0 & 0xFFFF0000u));
        atomicAdd(&acc[d1][co],     w1 * __uint_as_float(v1 << 16));
        atomicAdd(&acc[d1][co + 1], w1 * __uint_as_float(v1 & 0xFFFF0000u));
        atomicAdd(&acc[d2][co],     w2 * __uint_as_float(v2 << 16));
        atomicAdd(&acc[d2][co + 1], w2 * __uint_as_float(v2 & 0xFFFF0000u));
        atomicAdd(&acc[d3][co],     w3 * __uint_as_float(v3 << 16));
        atomicAdd(&acc[d3][co + 1], w3 * __uint_as_float(v3 & 0xFFFF0000u));
    }
    __syncthreads();

    // epilogue: thread t -> node t>>2, channels (t&3)*16 .. +15
    int nl = tid >> 2;
    int node = b * BN + nl;
    if (node < N) {
        float dd = dis[node];
        int c0 = (tid & 3) * 16;
#pragma unroll
        for (int j = 0; j < 4; ++j) {
            float4 a = *(const float4*)&acc[nl][c0 + 4 * j];
            float4 bb = *(const float4*)(bias + c0 + 4 * j);
            float4 o;
            o.x = 1.f / (1.f + __expf(-(a.x * dd + bb.x)));
            o.y = 1.f / (1.f + __expf(-(a.y * dd + bb.y)));
            o.z = 1.f / (1.f + __expf(-(a.z * dd + bb.z)));
            o.w = 1.f / (1.f + __expf(-(a.w * dd + bb.w)));
            *(float4*)(out + ((size_t)node << 6) + c0 + 4 * j) = o;
        }
    }
}

extern "C" void kernel_launch(void* const* d_in, const int* in_sizes, int n_in,
                              void* d_out, int out_size, void* d_ws, size_t ws_size,
                              hipStream_t stream) {
    const float* x   = (const float*)d_in[0];
    const int*   ei  = (const int*)d_in[1];
    const float* ew  = (const float*)d_in[2];
    const float* W   = (const float*)d_in[3];
    const float* b   = (const float*)d_in[4];
    float* out = (float*)d_out;

    const int N = in_sizes[0] / IN_CH;
    const int E = in_sizes[1] / 2;
    const int* row = ei;
    const int* col = ei + E;

    const int nbuck = (N + BN - 1) / BN;          // 1563
    const int per   = (E + NPART - 1) / NPART;    // 6250

    // ws: cnt[nbuck] | dis[N] | sparse[nbuck*CAP] uint2 | hb[N*64] bf16  (~29 MB)
    char* p = (char*)d_ws;
    int*   cnt     = (int*)p;    p += (size_t)nbuck * 4;
    float* dis     = (float*)p;  p += (size_t)N * 4;
    uint2* sparse  = (uint2*)p;  p += (size_t)nbuck * CAP * 8;
    unsigned short* hb = (unsigned short*)p;

    hipMemsetAsync(cnt, 0, (size_t)nbuck * 4, stream);

    k_part1<<<NPART, 1024, 0, stream>>>(row, col, ew, cnt, sparse, E, per, nbuck);
    k_gemm3<<<nbuck, 256, 0, stream>>>(x, W, sparse, cnt, dis, hb, N);
    k_agg<<<nbuck, 256, 0, stream>>>(sparse, cnt, dis, hb, b, out, N, nbuck);
}

// Round 9
// 210.396 us; speedup vs baseline: 3.6469x; 3.6469x over previous
//
#include <hip/hip_runtime.h>

#define IN_CH 128
#define OUT_CH 64
#define BN 64         // nodes per bucket
#define CAP 1280      // sparse slots per bucket (mean 1024, sigma 32 -> 8 sigma)
#define NPART 256     // partition blocks

typedef __attribute__((ext_vector_type(8))) short short8;
typedef __attribute__((ext_vector_type(4))) float f32x4;

__device__ __forceinline__ unsigned short f2bf(float f) {
    unsigned u = __float_as_uint(f);
    unsigned r = (u + 0x7FFFu + ((u >> 16) & 1u)) >> 16;   // RNE
    return (unsigned short)r;
}

// ---------- part1: fused hist + range-reservation + scatter (sparse) ----------
__global__ __launch_bounds__(1024) void k_part1(const int* __restrict__ row,
                                                const int* __restrict__ col,
                                                const float* __restrict__ ew,
                                                int* __restrict__ cnt,
                                                uint2* __restrict__ sparse,
                                                int E, int per, int nbuck) {
    __shared__ int lh[1600];
    __shared__ int cur[1600];
    int tid = threadIdx.x;
    for (int i = tid; i < nbuck; i += 1024) lh[i] = 0;
    __syncthreads();
    int e0 = blockIdx.x * per;
    int e1 = min(E, e0 + per);
    for (int e = e0 + tid; e < e1; e += 1024)
        atomicAdd(&lh[col[e] >> 6], 1);
    __syncthreads();
    for (int bin = tid; bin < nbuck; bin += 1024) {
        int c = lh[bin];
        int base = c ? atomicAdd(&cnt[bin], c) : 0;   // reserve range in bucket
        cur[bin] = bin * CAP + base;
    }
    __syncthreads();
    int lim = nbuck * CAP;
    for (int e = e0 + tid; e < e1; e += 1024) {
        int r = row[e];
        int c = col[e];
        float w = ew[e];
        int bin = c >> 6;
        int p = atomicAdd(&cur[bin], 1);
        if (p < lim)   // safety clamp (never triggers at 8 sigma)
            sparse[p] = make_uint2((unsigned)r | ((unsigned)(c & 63) << 17),
                                   __float_as_uint(w));
    }
}

// ---------- gemm3: fused per-bucket degree + dis + MFMA bf16 GEMM ----------
__global__ __launch_bounds__(256) void k_gemm3(const float* __restrict__ x,
                                               const float* __restrict__ W,
                                               const uint2* __restrict__ sparse,
                                               const int* __restrict__ cnt,
                                               float* __restrict__ dis,
                                               unsigned short* __restrict__ hb,
                                               int N) {
    __shared__ unsigned short Wl[64][136];   // W^T bf16, padded: row stride 272B (17x16B)
    __shared__ float degs[BN];

    int tid = threadIdx.x;
    int b = blockIdx.x;
    int row0 = b * BN;

    if (tid < BN) degs[tid] = 0.f;
    __syncthreads();

    // stage W transposed to bf16 LDS (one-time, L1/L2-hot) ...
    for (int i = tid; i < 2048; i += 256) {
        int k = i >> 4;             // 0..127
        int n4 = (i & 15) << 2;     // 0,4,...,60
        float4 v = *(const float4*)(W + (size_t)k * OUT_CH + n4);
        Wl[n4 + 0][k] = f2bf(v.x);
        Wl[n4 + 1][k] = f2bf(v.y);
        Wl[n4 + 2][k] = f2bf(v.z);
        Wl[n4 + 3][k] = f2bf(v.w);
    }
    // ... overlapped with per-bucket weighted degree from sparse
    // (~16 ds_add_f32 wave-instrs per block: harmless; k_agg's 2048/block was the disaster)
    {
        int m = min(cnt[b], CAP);
        int sbase = b * CAP;
        for (int i = tid; i < m; i += 256) {
            uint2 r = sparse[sbase + i];
            atomicAdd(&degs[(r.x >> 17) & 63], __uint_as_float(r.y));
        }
    }
    __syncthreads();

    if (tid < BN) {
        float d = degs[tid];
        float dv = (d > 0.f) ? rsqrtf(d) : 0.f;
        int node = row0 + tid;
        if (node < N) dis[node] = dv;
        degs[tid] = dv;              // reuse as dis for epilogue (sync'd below)
    }

    // MFMA: wave w owns rows [16w, 16w+16); 4 n-tiles of 16 cover OUT=64
    int lane = tid & 63;
    int wv = tid >> 6;
    int r0l = 16 * wv;
    int cn = lane & 15;
    int rg = lane >> 4;              // k-group / row-group

    f32x4 acc0 = {0.f, 0.f, 0.f, 0.f};
    f32x4 acc1 = {0.f, 0.f, 0.f, 0.f};
    f32x4 acc2 = {0.f, 0.f, 0.f, 0.f};
    f32x4 acc3 = {0.f, 0.f, 0.f, 0.f};

    int arow = row0 + r0l + cn;      // A-fragment row for this lane
#pragma unroll
    for (int ks = 0; ks < 4; ++ks) {
        int k0 = ks * 32 + rg * 8;
        short8 a = {};
        if (arow < N) {
            const float* xp = x + (size_t)arow * IN_CH + k0;
            float4 va = *(const float4*)(xp);
            float4 vb = *(const float4*)(xp + 4);
            a[0] = (short)f2bf(va.x); a[1] = (short)f2bf(va.y);
            a[2] = (short)f2bf(va.z); a[3] = (short)f2bf(va.w);
            a[4] = (short)f2bf(vb.x); a[5] = (short)f2bf(vb.y);
            a[6] = (short)f2bf(vb.z); a[7] = (short)f2bf(vb.w);
        }
        short8 b0 = *(const short8*)&Wl[ 0 + cn][k0];
        short8 b1 = *(const short8*)&Wl[16 + cn][k0];
        short8 b2 = *(const short8*)&Wl[32 + cn][k0];
        short8 b3 = *(const short8*)&Wl[48 + cn][k0];
        acc0 = __builtin_amdgcn_mfma_f32_16x16x32_bf16(a, b0, acc0, 0, 0, 0);
        acc1 = __builtin_amdgcn_mfma_f32_16x16x32_bf16(a, b1, acc1, 0, 0, 0);
        acc2 = __builtin_amdgcn_mfma_f32_16x16x32_bf16(a, b2, acc2, 0, 0, 0);
        acc3 = __builtin_amdgcn_mfma_f32_16x16x32_bf16(a, b3, acc3, 0, 0, 0);
    }
    __syncthreads();   // dis values in degs[] now visible

    // C/D layout (m89-verified): col = lane&15, row = (lane>>4)*4 + reg
#pragma unroll
    for (int r = 0; r < 4; ++r) {
        int row_l = r0l + rg * 4 + r;
        int grow = row0 + row_l;
        if (grow < N) {
            float sc = degs[row_l];
            unsigned short* hp = hb + (size_t)grow * OUT_CH + cn;
            hp[ 0] = f2bf(acc0[r] * sc);
            hp[16] = f2bf(acc1[r] * sc);
            hp[32] = f2bf(acc2[r] * sc);
            hp[48] = f2bf(acc3[r] * sc);
        }
    }
}

// ---------- sort4: hist + padded scan + regroup + PAIRED register aggregation ----------
// vs sort3: (1) each half-wave processes a node PAIR (nA, nA+32) with branchless
// masked 4+4 unroll -> 8 independent gathers in flight (2x MLP);
// (2) per-node segments padded to x4 with zero-weight records -> no tails;
// (3) no recbuf staging (pass B re-reads sparse from global, L2-hot) -> 13.5 KB LDS.
// Register accumulation only — LDS f32 atomics at density are a 12x disaster (r6).
__global__ __launch_bounds__(256) void k_sort4(const uint2* __restrict__ sparse,
                                               const int* __restrict__ cnt,
                                               const float* __restrict__ dis,
                                               const unsigned short* __restrict__ hb,
                                               const float* __restrict__ bias,
                                               float* __restrict__ out,
                                               int N, int nbuck) {
    __shared__ uint2 recbuf2[CAP + 256];   // padded segments (max m+192+4 <= 1476)
    __shared__ int hist[BN];
    __shared__ int iters[BN];              // padded count / 4
    __shared__ int starts[BN];
    __shared__ int cur[BN];

    int b = blockIdx.x;
    int tid = threadIdx.x;
    int sbase = b * CAP;
    int m = min(cnt[b], CAP);

    if (tid < BN) hist[tid] = 0;
    __syncthreads();

    // pass A: histogram only
    for (int i = tid; i < m; i += 256)
        atomicAdd(&hist[(sparse[sbase + i].x >> 17) & 63], 1);
    __syncthreads();

    // single-wave inclusive scan over x4-padded counts
    if (tid < 64) {
        int h = hist[tid];
        int hp = (h + 3) & ~3;
        int v = hp;
#pragma unroll
        for (int d = 1; d < 64; d <<= 1) {
            int t = __shfl_up(v, d, 64);
            if (tid >= d) v += t;
        }
        starts[tid] = v - hp;
        cur[tid] = v - hp;
        iters[tid] = hp >> 2;
        if (tid == 63) {                   // zero 4 slots past the end (deg==0 guard)
            recbuf2[v + 0] = make_uint2(0u, 0u);
            recbuf2[v + 1] = make_uint2(0u, 0u);
            recbuf2[v + 2] = make_uint2(0u, 0u);
            recbuf2[v + 3] = make_uint2(0u, 0u);
        }
    }
    __syncthreads();

    // zero-pad per-node gaps (disjoint from scatter targets)
    if (tid < BN) {
        int s = starts[tid] + hist[tid];
        int e = starts[tid] + (iters[tid] << 2);
        for (int k = s; k < e; ++k) recbuf2[k] = make_uint2(0u, 0u);
    }
    // pass B: re-read sparse (L2-hot), scatter grouped-by-node
    for (int i = tid; i < m; i += 256) {
        uint2 r = sparse[sbase + i];
        int dl = (r.x >> 17) & 63;
        int p = atomicAdd(&cur[dl], 1);
        recbuf2[p] = make_uint2(r.x & 0x1FFFF, r.y);
    }
    __syncthreads();

    // agg: half-wave per node pair, branchless masked 4+4 unroll, fused epilogue
    int hwl = tid >> 5;                    // 0..7
    int lanep = tid & 31;
    unsigned co = 2u * (unsigned)lanep;

    for (int np = hwl; np < 32; np += 8) {
        int nA = np, nB = np + 32;
        int eA = starts[nA], cA = iters[nA];
        int eB = starts[nB], cB = iters[nB];
        int it = max(cA, cB);
        float axA = 0.f, ayA = 0.f, axB = 0.f, ayB = 0.f;

        for (int k = 0; k < it; ++k) {
            int kA = min(k, cA - 1); if (kA < 0) kA = 0;
            int kB = min(k, cB - 1); if (kB < 0) kB = 0;
            bool mA = k < cA;
            bool mB = k < cB;
            int ea = eA + 4 * kA;
            int eb = eB + 4 * kB;
            // 8 record reads (LDS, contiguous) then 8 independent gathers
            uint2 a0 = recbuf2[ea + 0], a1 = recbuf2[ea + 1];
            uint2 a2 = recbuf2[ea + 2], a3 = recbuf2[ea + 3];
            uint2 b0 = recbuf2[eb + 0], b1 = recbuf2[eb + 1];
            uint2 b2 = recbuf2[eb + 2], b3 = recbuf2[eb + 3];
            unsigned va0 = *(const unsigned*)(hb + (((size_t)a0.x) << 6) + co);
            unsigned va1 = *(const unsigned*)(hb + (((size_t)a1.x) << 6) + co);
            unsigned va2 = *(const unsigned*)(hb + (((size_t)a2.x) << 6) + co);
            unsigned va3 = *(const unsigned*)(hb + (((size_t)a3.x) << 6) + co);
            unsigned vb0 = *(const unsigned*)(hb + (((size_t)b0.x) << 6) + co);
            unsigned vb1 = *(const unsigned*)(hb + (((size_t)b1.x) << 6) + co);
            unsigned vb2 = *(const unsigned*)(hb + (((size_t)b2.x) << 6) + co);
            unsigned vb3 = *(const unsigned*)(hb + (((size_t)b3.x) << 6) + co);
            float wa0 = mA ? __uint_as_float(a0.y) : 0.f;
            float wa1 = mA ? __uint_as_float(a1.y) : 0.f;
            float wa2 = mA ? __uint_as_float(a2.y) : 0.f;
            float wa3 = mA ? __uint_as_float(a3.y) : 0.f;
            float wb0 = mB ? __uint_as_float(b0.y) : 0.f;
            float wb1 = mB ? __uint_as_float(b1.y) : 0.f;
            float wb2 = mB ? __uint_as_float(b2.y) : 0.f;
            float wb3 = mB ? __uint_as_float(b3.y) : 0.f;
            axA += wa0 * __uint_as_float(va0 << 16);
            ayA += wa0 * __uint_as_float(va0 & 0xFFFF0000u);
            axA += wa1 * __uint_as_float(va1 << 16);
            ayA += wa1 * __uint_as_float(va1 & 0xFFFF0000u);
            axA += wa2 * __uint_as_float(va2 << 16);
            ayA += wa2 * __uint_as_float(va2 & 0xFFFF0000u);
            axA += wa3 * __uint_as_float(va3 << 16);
            ayA += wa3 * __uint_as_float(va3 & 0xFFFF0000u);
            axB += wb0 * __uint_as_float(vb0 << 16);
            ayB += wb0 * __uint_as_float(vb0 & 0xFFFF0000u);
            axB += wb1 * __uint_as_float(vb1 << 16);
            ayB += wb1 * __uint_as_float(vb1 & 0xFFFF0000u);
            axB += wb2 * __uint_as_float(vb2 << 16);
            ayB += wb2 * __uint_as_float(vb2 & 0xFFFF0000u);
            axB += wb3 * __uint_as_float(vb3 << 16);
            ayB += wb3 * __uint_as_float(vb3 & 0xFFFF0000u);
        }

        float2 bb = *(const float2*)(bias + co);
        int nodeA = b * BN + nA;
        int nodeB = b * BN + nB;
        if (nodeA < N) {
            float dd = dis[nodeA];
            float2 o;
            o.x = 1.f / (1.f + __expf(-(axA * dd + bb.x)));
            o.y = 1.f / (1.f + __expf(-(ayA * dd + bb.y)));
            *(float2*)(out + ((size_t)nodeA << 6) + co) = o;
        }
        if (nodeB < N) {
            float dd = dis[nodeB];
            float2 o;
            o.x = 1.f / (1.f + __expf(-(axB * dd + bb.x)));
            o.y = 1.f / (1.f + __expf(-(ayB * dd + bb.y)));
            *(float2*)(out + ((size_t)nodeB << 6) + co) = o;
        }
    }
}

extern "C" void kernel_launch(void* const* d_in, const int* in_sizes, int n_in,
                              void* d_out, int out_size, void* d_ws, size_t ws_size,
                              hipStream_t stream) {
    const float* x   = (const float*)d_in[0];
    const int*   ei  = (const int*)d_in[1];
    const float* ew  = (const float*)d_in[2];
    const float* W   = (const float*)d_in[3];
    const float* b   = (const float*)d_in[4];
    float* out = (float*)d_out;

    const int N = in_sizes[0] / IN_CH;
    const int E = in_sizes[1] / 2;
    const int* row = ei;
    const int* col = ei + E;

    const int nbuck = (N + BN - 1) / BN;          // 1563
    const int per   = (E + NPART - 1) / NPART;    // 6250

    // ws: cnt[nbuck] | dis[N] | sparse[nbuck*CAP] uint2 | hb[N*64] bf16  (~29 MB)
    char* p = (char*)d_ws;
    int*   cnt     = (int*)p;    p += (size_t)nbuck * 4;
    float* dis     = (float*)p;  p += (size_t)N * 4;
    uint2* sparse  = (uint2*)p;  p += (size_t)nbuck * CAP * 8;
    unsigned short* hb = (unsigned short*)p;

    hipMemsetAsync(cnt, 0, (size_t)nbuck * 4, stream);

    k_part1<<<NPART, 1024, 0, stream>>>(row, col, ew, cnt, sparse, E, per, nbuck);
    k_gemm3<<<nbuck, 256, 0, stream>>>(x, W, sparse, cnt, dis, hb, N);
    k_sort4<<<nbuck, 256, 0, stream>>>(sparse, cnt, dis, hb, b, out, N, nbuck);
}

// Round 11
// 192.145 us; speedup vs baseline: 3.9933x; 1.0950x over previous
//
#include <hip/hip_runtime.h>

#define IN_CH 128
#define OUT_CH 64
#define BN 64         // nodes per bucket
#define CAP 1280      // sparse slots per bucket (mean 1024, sigma 32 -> 8 sigma)
#define NPART 256     // partition blocks

typedef __attribute__((ext_vector_type(8))) short short8;
typedef __attribute__((ext_vector_type(4))) float f32x4;

__device__ __forceinline__ unsigned short f2bf(float f) {
    unsigned u = __float_as_uint(f);
    unsigned r = (u + 0x7FFFu + ((u >> 16) & 1u)) >> 16;   // RNE
    return (unsigned short)r;
}

// ---------- part2: LDS counting-sort partition -> COALESCED sparse writes ----------
// Replaces part1. part1's scatter was 1.6M random 8B stores (~64 lines/wave,
// ~100MB write-line allocation). Here each block sorts its 6250 edges by bucket
// in LDS, then writes each bucket's run contiguously (runs ~4 rec = 32B) with
// consecutive threads on consecutive addresses. Reads stay fully coalesced.
__global__ __launch_bounds__(1024) void k_part2(const int* __restrict__ row,
                                                const int* __restrict__ col,
                                                const float* __restrict__ ew,
                                                int* __restrict__ cnt,
                                                uint2* __restrict__ sparse,
                                                int E, int per, int nbuck) {
    __shared__ uint2 srec[6272];            // 50.2 KB sorted records
    __shared__ unsigned short sbin[6272];   // 12.5 KB bucket id per record
    __shared__ int loff[1600];              // counts -> exclusive offsets (in place)
    __shared__ int lcur[1600];
    __shared__ int gbase[1600];
    __shared__ int wpart[16];
    __shared__ int stot;

    int tid = threadIdx.x;
    int e0 = blockIdx.x * per;
    int e1 = min(E, e0 + per);
    int nloc = e1 - e0;

    for (int i = tid; i < nbuck; i += 1024) loff[i] = 0;
    __syncthreads();

    // hist
    for (int e = e0 + tid; e < e1; e += 1024)
        atomicAdd(&loff[col[e] >> 6], 1);
    __syncthreads();

    // exclusive scan over nbuck bins: 2 bins/thread, wave shfl scan + wave partials
    int b0 = 2 * tid, b1 = 2 * tid + 1;
    int s0 = (b0 < nbuck) ? loff[b0] : 0;
    int s1 = (b1 < nbuck) ? loff[b1] : 0;
    int ts = s0 + s1;
    int lane = tid & 63, wv = tid >> 6;
    int v = ts;
#pragma unroll
    for (int d = 1; d < 64; d <<= 1) { int t = __shfl_up(v, d, 64); if (lane >= d) v += t; }
    if (lane == 63) wpart[wv] = v;
    __syncthreads();                        // also fences all loff reads above
    if (tid < 16) {
        int vv = wpart[tid];
#pragma unroll
        for (int d = 1; d < 16; d <<= 1) { int t = __shfl_up(vv, d, 16); if (tid >= d) vv += t; }
        wpart[tid] = vv;
        if (tid == 15) stot = vv;
    }
    __syncthreads();
    int excl = ((wv > 0) ? wpart[wv - 1] : 0) + (v - ts);
    if (b0 < nbuck) loff[b0] = excl;
    if (b1 < nbuck) loff[b1] = excl + s0;
    __syncthreads();

    // reserve global ranges per non-empty bucket + init running cursors
    int total = stot;
    for (int b = tid; b < nbuck; b += 1024) {
        int nxt = (b + 1 < nbuck) ? loff[b + 1] : total;
        int c = nxt - loff[b];
        gbase[b] = c ? atomicAdd(&cnt[b], c) : 0;
        lcur[b] = loff[b];
    }
    __syncthreads();

    // scatter into LDS (grouped by bucket)
    for (int e = e0 + tid; e < e1; e += 1024) {
        int r = row[e];
        int c = col[e];
        float w = ew[e];
        int bin = c >> 6;
        int p = atomicAdd(&lcur[bin], 1);
        srec[p] = make_uint2((unsigned)r | ((unsigned)(c & 63) << 17),
                             __float_as_uint(w));
        sbin[p] = (unsigned short)bin;
    }
    __syncthreads();

    // coalesced write-out: consecutive i -> consecutive slots within a bucket run
    for (int i = tid; i < nloc; i += 1024) {
        int bin = sbin[i];
        int k = i - loff[bin];
        int gp = gbase[bin] + k;
        if (gp < CAP)                        // safety clamp (never at 8 sigma)
            sparse[(size_t)bin * CAP + gp] = srec[i];
    }
}

// ---------- gemm3: fused per-bucket degree + dis + MFMA bf16 GEMM (unchanged) ----------
__global__ __launch_bounds__(256) void k_gemm3(const float* __restrict__ x,
                                               const float* __restrict__ W,
                                               const uint2* __restrict__ sparse,
                                               const int* __restrict__ cnt,
                                               float* __restrict__ dis,
                                               unsigned short* __restrict__ hb,
                                               int N) {
    __shared__ unsigned short Wl[64][136];   // W^T bf16, padded: row stride 272B (17x16B)
    __shared__ float degs[BN];

    int tid = threadIdx.x;
    int b = blockIdx.x;
    int row0 = b * BN;

    if (tid < BN) degs[tid] = 0.f;
    __syncthreads();

    for (int i = tid; i < 2048; i += 256) {
        int k = i >> 4;
        int n4 = (i & 15) << 2;
        float4 v = *(const float4*)(W + (size_t)k * OUT_CH + n4);
        Wl[n4 + 0][k] = f2bf(v.x);
        Wl[n4 + 1][k] = f2bf(v.y);
        Wl[n4 + 2][k] = f2bf(v.z);
        Wl[n4 + 3][k] = f2bf(v.w);
    }
    {
        int m = min(cnt[b], CAP);
        int sbase = b * CAP;
        for (int i = tid; i < m; i += 256) {
            uint2 r = sparse[sbase + i];
            atomicAdd(&degs[(r.x >> 17) & 63], __uint_as_float(r.y));
        }
    }
    __syncthreads();

    if (tid < BN) {
        float d = degs[tid];
        float dv = (d > 0.f) ? rsqrtf(d) : 0.f;
        int node = row0 + tid;
        if (node < N) dis[node] = dv;
        degs[tid] = dv;
    }

    int lane = tid & 63;
    int wv = tid >> 6;
    int r0l = 16 * wv;
    int cn = lane & 15;
    int rg = lane >> 4;

    f32x4 acc0 = {0.f, 0.f, 0.f, 0.f};
    f32x4 acc1 = {0.f, 0.f, 0.f, 0.f};
    f32x4 acc2 = {0.f, 0.f, 0.f, 0.f};
    f32x4 acc3 = {0.f, 0.f, 0.f, 0.f};

    int arow = row0 + r0l + cn;
#pragma unroll
    for (int ks = 0; ks < 4; ++ks) {
        int k0 = ks * 32 + rg * 8;
        short8 a = {};
        if (arow < N) {
            const float* xp = x + (size_t)arow * IN_CH + k0;
            float4 va = *(const float4*)(xp);
            float4 vb = *(const float4*)(xp + 4);
            a[0] = (short)f2bf(va.x); a[1] = (short)f2bf(va.y);
            a[2] = (short)f2bf(va.z); a[3] = (short)f2bf(va.w);
            a[4] = (short)f2bf(vb.x); a[5] = (short)f2bf(vb.y);
            a[6] = (short)f2bf(vb.z); a[7] = (short)f2bf(vb.w);
        }
        short8 b0 = *(const short8*)&Wl[ 0 + cn][k0];
        short8 b1 = *(const short8*)&Wl[16 + cn][k0];
        short8 b2 = *(const short8*)&Wl[32 + cn][k0];
        short8 b3 = *(const short8*)&Wl[48 + cn][k0];
        acc0 = __builtin_amdgcn_mfma_f32_16x16x32_bf16(a, b0, acc0, 0, 0, 0);
        acc1 = __builtin_amdgcn_mfma_f32_16x16x32_bf16(a, b1, acc1, 0, 0, 0);
        acc2 = __builtin_amdgcn_mfma_f32_16x16x32_bf16(a, b2, acc2, 0, 0, 0);
        acc3 = __builtin_amdgcn_mfma_f32_16x16x32_bf16(a, b3, acc3, 0, 0, 0);
    }
    __syncthreads();

#pragma unroll
    for (int r = 0; r < 4; ++r) {
        int row_l = r0l + rg * 4 + r;
        int grow = row0 + row_l;
        if (grow < N) {
            float sc = degs[row_l];
            unsigned short* hp = hb + (size_t)grow * OUT_CH + cn;
            hp[ 0] = f2bf(acc0[r] * sc);
            hp[16] = f2bf(acc1[r] * sc);
            hp[32] = f2bf(acc2[r] * sc);
            hp[48] = f2bf(acc3[r] * sc);
        }
    }
}

// ---------- sort3: fused group-in-LDS + register aggregation + epilogue ----------
// (reverted to the measured 51.2 µs version; sort4's paired/padded variant was 54.9)
__global__ __launch_bounds__(256) void k_sort3(const uint2* __restrict__ sparse,
                                               const int* __restrict__ cnt,
                                               const float* __restrict__ dis,
                                               const unsigned short* __restrict__ hb,
                                               const float* __restrict__ bias,
                                               float* __restrict__ out,
                                               int N, int nbuck) {
    __shared__ uint2 recbuf[CAP];
    __shared__ uint2 recbuf2[CAP];
    __shared__ int hist[BN];
    __shared__ int cur[BN];
    __shared__ int starts[BN];

    int b = blockIdx.x;
    int tid = threadIdx.x;
    int sbase = b * CAP;
    int m = min(cnt[b], CAP);

    if (tid < BN) hist[tid] = 0;
    __syncthreads();

    for (int i = tid; i < m; i += 256) {
        uint2 r = sparse[sbase + i];
        recbuf[i] = r;
        atomicAdd(&hist[(r.x >> 17) & 63], 1);
    }
    __syncthreads();

    if (tid < 64) {
        int h = hist[tid];
        int v = h;
#pragma unroll
        for (int d = 1; d < 64; d <<= 1) {
            int t = __shfl_up(v, d, 64);
            if (tid >= d) v += t;
        }
        int excl = v - h;
        cur[tid] = excl;
        starts[tid] = excl;
    }
    __syncthreads();

    for (int i = tid; i < m; i += 256) {
        uint2 r = recbuf[i];
        int dl = (r.x >> 17) & 63;
        int p = atomicAdd(&cur[dl], 1);
        recbuf2[p] = make_uint2(r.x & 0x1FFFF, r.y);
    }
    __syncthreads();

    int hwl = tid >> 5;
    int lanep = tid & 31;
    unsigned co = 2u * (unsigned)lanep;
    for (int nl = hwl; nl < BN; nl += 8) {
        int node = b * BN + nl;
        if (node >= N) break;
        int e = starts[nl];
        int e1 = e + hist[nl];
        float accx = 0.f, accy = 0.f;
        for (; e + 3 < e1; e += 4) {
            uint2 p0 = recbuf2[e];
            uint2 p1 = recbuf2[e + 1];
            uint2 p2 = recbuf2[e + 2];
            uint2 p3 = recbuf2[e + 3];
            unsigned v0 = *(const unsigned*)(hb + (p0.x << 6) + co);
            unsigned v1 = *(const unsigned*)(hb + (p1.x << 6) + co);
            unsigned v2 = *(const unsigned*)(hb + (p2.x << 6) + co);
            unsigned v3 = *(const unsigned*)(hb + (p3.x << 6) + co);
            float w0 = __uint_as_float(p0.y), w1 = __uint_as_float(p1.y);
            float w2 = __uint_as_float(p2.y), w3 = __uint_as_float(p3.y);
            accx += w0 * __uint_as_float(v0 << 16);
            accy += w0 * __uint_as_float(v0 & 0xFFFF0000u);
            accx += w1 * __uint_as_float(v1 << 16);
            accy += w1 * __uint_as_float(v1 & 0xFFFF0000u);
            accx += w2 * __uint_as_float(v2 << 16);
            accy += w2 * __uint_as_float(v2 & 0xFFFF0000u);
            accx += w3 * __uint_as_float(v3 << 16);
            accy += w3 * __uint_as_float(v3 & 0xFFFF0000u);
        }
        for (; e < e1; ++e) {
            uint2 p = recbuf2[e];
            unsigned v = *(const unsigned*)(hb + (p.x << 6) + co);
            float w = __uint_as_float(p.y);
            accx += w * __uint_as_float(v << 16);
            accy += w * __uint_as_float(v & 0xFFFF0000u);
        }
        float dd = dis[node];
        float2 bb = *(const float2*)(bias + co);
        float2 o;
        o.x = 1.f / (1.f + __expf(-(accx * dd + bb.x)));
        o.y = 1.f / (1.f + __expf(-(accy * dd + bb.y)));
        *(float2*)(out + ((size_t)node << 6) + co) = o;
    }
}

extern "C" void kernel_launch(void* const* d_in, const int* in_sizes, int n_in,
                              void* d_out, int out_size, void* d_ws, size_t ws_size,
                              hipStream_t stream) {
    const float* x   = (const float*)d_in[0];
    const int*   ei  = (const int*)d_in[1];
    const float* ew  = (const float*)d_in[2];
    const float* W   = (const float*)d_in[3];
    const float* b   = (const float*)d_in[4];
    float* out = (float*)d_out;

    const int N = in_sizes[0] / IN_CH;
    const int E = in_sizes[1] / 2;
    const int* row = ei;
    const int* col = ei + E;

    const int nbuck = (N + BN - 1) / BN;          // 1563
    const int per   = (E + NPART - 1) / NPART;    // 6250

    // ws: cnt[nbuck] | dis[N] | sparse[nbuck*CAP] uint2 | hb[N*64] bf16  (~29 MB)
    char* p = (char*)d_ws;
    int*   cnt     = (int*)p;    p += (size_t)nbuck * 4;
    float* dis     = (float*)p;  p += (size_t)N * 4;
    uint2* sparse  = (uint2*)p;  p += (size_t)nbuck * CAP * 8;
    unsigned short* hb = (unsigned short*)p;

    hipMemsetAsync(cnt, 0, (size_t)nbuck * 4, stream);

    k_part2<<<NPART, 1024, 0, stream>>>(row, col, ew, cnt, sparse, E, per, nbuck);
    k_gemm3<<<nbuck, 256, 0, stream>>>(x, W, sparse, cnt, dis, hb, N);
    k_sort3<<<nbuck, 256, 0, stream>>>(sparse, cnt, dis, hb, b, out, N, nbuck);
}